// Round 1
// baseline (46.792 us; speedup 1.0000x reference)
//
#include <hip/hip_runtime.h>

// Problem shape (from reference setup_inputs): x[n_experts=8][n_task=8][batch=1024][dim=512] fp32.
// Output: out[t][b][e][d] = ((t*1024+b)*8+e)*512+d, orthonormalized rows per (t,b) sample.
// One wave (64 lanes) per sample; whole 8x512 matrix lives in registers (8 floats/lane/vector).

#define NE 8
#define DIM 512
#define NSAMP 8192  // n_task * batch = 8 * 1024

__device__ __forceinline__ float wave_sum(float p) {
#pragma unroll
    for (int off = 32; off > 0; off >>= 1)
        p += __shfl_xor(p, off, 64);
    return p;
}

__global__ __launch_bounds__(256) void gs_kernel(const float* __restrict__ x,
                                                 float* __restrict__ out) {
    const int lane = threadIdx.x & 63;
    const int w = blockIdx.x * 4 + (threadIdx.x >> 6);  // sample id in [0, 8192)
    const int t = w >> 10;        // n_task index
    const int b = w & 1023;       // batch index

    // Load 8 vectors: per lane, elements d = c*256 + lane*4 + k  (two coalesced float4 loads each)
    float v[NE][8];
#pragma unroll
    for (int e = 0; e < NE; ++e) {
        const float* src = x + ((size_t)(e * 8 + t) * 1024 + b) * DIM;
#pragma unroll
        for (int c = 0; c < 2; ++c) {
            float4 f = *reinterpret_cast<const float4*>(src + c * 256 + lane * 4);
            v[e][c * 4 + 0] = f.x;
            v[e][c * 4 + 1] = f.y;
            v[e][c * 4 + 2] = f.z;
            v[e][c * 4 + 3] = f.w;
        }
    }

    // Classical Gram-Schmidt, matching the reference:
    //   coeffs_j = <basis_j, v_i>  (all against ORIGINAL v_i)
    //   v_i -= sum_j coeffs_j * basis_j
    //   v_i /= ||v_i||
#pragma unroll
    for (int i = 0; i < NE; ++i) {
        float coef[NE];
#pragma unroll
        for (int j = 0; j < NE; ++j) {
            if (j < i) {
                float p = 0.f;
#pragma unroll
                for (int k = 0; k < 8; ++k) p = fmaf(v[j][k], v[i][k], p);
                coef[j] = wave_sum(p);
            }
        }
#pragma unroll
        for (int k = 0; k < 8; ++k) {
            float acc = 0.f;
#pragma unroll
            for (int j = 0; j < NE; ++j) {
                if (j < i) acc = fmaf(coef[j], v[j][k], acc);
            }
            v[i][k] -= acc;
        }
        // normalize
        float p = 0.f;
#pragma unroll
        for (int k = 0; k < 8; ++k) p = fmaf(v[i][k], v[i][k], p);
        float nrm2 = wave_sum(p);
        float inv = 1.0f / sqrtf(nrm2);
#pragma unroll
        for (int k = 0; k < 8; ++k) v[i][k] *= inv;
    }

    // Store: out[((t*1024+b)*8+e)*512 + d], same coalesced float4 pattern
#pragma unroll
    for (int e = 0; e < NE; ++e) {
        float* dst = out + ((size_t)w * NE + e) * DIM;
#pragma unroll
        for (int c = 0; c < 2; ++c) {
            float4 f;
            f.x = v[e][c * 4 + 0];
            f.y = v[e][c * 4 + 1];
            f.z = v[e][c * 4 + 2];
            f.w = v[e][c * 4 + 3];
            *reinterpret_cast<float4*>(dst + c * 256 + lane * 4) = f;
        }
    }
}

extern "C" void kernel_launch(void* const* d_in, const int* in_sizes, int n_in,
                              void* d_out, int out_size, void* d_ws, size_t ws_size,
                              hipStream_t stream) {
    const float* x = (const float*)d_in[0];
    float* out = (float*)d_out;
    // 8192 samples, 1 wave each, 4 waves per 256-thread block -> 2048 blocks
    gs_kernel<<<NSAMP / 4, 256, 0, stream>>>(x, out);
}